// Round 1
// baseline (383.436 us; speedup 1.0000x reference)
//
#include <hip/hip_runtime.h>

#define NV 50000
#define BDIM 64
#define DIN 1024
#define KFAN 32
#define NLAYERS 3
#define DOUT 256

constexpr int L0_BN = 64;
constexpr int L0_KC = 64;

// h0[n][b] = relu(sum_d W0[n][d]*x[b][d] + b0[n]),  h0 is [N][64]
__global__ __launch_bounds__(256) void layer0_gemm(
    const float* __restrict__ x, const float* __restrict__ W0,
    const float* __restrict__ b0, float* __restrict__ h)
{
  __shared__ float ws[L0_BN][L0_KC + 1];  // [n_local][k]
  __shared__ float xs[BDIM][L0_KC + 1];   // [b][k]
  const int t = threadIdx.x;
  const int n0 = blockIdx.x * L0_BN;
  const int tx = t & 15;   // b-group: b = tx*4 + i
  const int ty = t >> 4;   // n-group: n = n0 + ty*4 + j
  float acc[4][4] = {};    // [j][i]

  for (int kc = 0; kc < DIN; kc += L0_KC) {
#pragma unroll
    for (int rep = 0; rep < 4; ++rep) {
      int idx = rep * 256 + t;
      int row = idx >> 4;
      int c4 = (idx & 15) * 4;
      int n = n0 + row;
      float4 wv = make_float4(0.f, 0.f, 0.f, 0.f);
      if (n < NV) wv = *(const float4*)(W0 + (size_t)n * DIN + kc + c4);
      ws[row][c4 + 0] = wv.x; ws[row][c4 + 1] = wv.y;
      ws[row][c4 + 2] = wv.z; ws[row][c4 + 3] = wv.w;
      float4 xv = *(const float4*)(x + (size_t)row * DIN + kc + c4);
      xs[row][c4 + 0] = xv.x; xs[row][c4 + 1] = xv.y;
      xs[row][c4 + 2] = xv.z; xs[row][c4 + 3] = xv.w;
    }
    __syncthreads();
#pragma unroll 8
    for (int kk = 0; kk < L0_KC; ++kk) {
      float wr[4], xr[4];
#pragma unroll
      for (int j = 0; j < 4; ++j) wr[j] = ws[ty * 4 + j][kk];
#pragma unroll
      for (int i = 0; i < 4; ++i) xr[i] = xs[tx * 4 + i][kk];
#pragma unroll
      for (int j = 0; j < 4; ++j)
#pragma unroll
        for (int i = 0; i < 4; ++i)
          acc[j][i] = fmaf(wr[j], xr[i], acc[j][i]);
    }
    __syncthreads();
  }
#pragma unroll
  for (int j = 0; j < 4; ++j) {
    int n = n0 + ty * 4 + j;
    if (n < NV) {
      float bias = b0[n];
      float4 o;
      o.x = fmaxf(acc[j][0] + bias, 0.f);
      o.y = fmaxf(acc[j][1] + bias, 0.f);
      o.z = fmaxf(acc[j][2] + bias, 0.f);
      o.w = fmaxf(acc[j][3] + bias, 0.f);
      *(float4*)(h + (size_t)n * BDIM + tx * 4) = o;
    }
  }
}

// h_new[n][b] = relu(sum_k wv[n][k] * h[src[n][k]][b]); one wave per n
__global__ __launch_bounds__(256) void sparse_layer(
    const float* __restrict__ hin, const float* __restrict__ wv,
    const int* __restrict__ src, float* __restrict__ hout)
{
  const int lane = threadIdx.x & 63;
  int n = blockIdx.x * 4 + (threadIdx.x >> 6);
  n = __builtin_amdgcn_readfirstlane(n);  // wave-uniform -> s_loads below
  const float* wrow = wv + (size_t)n * KFAN;
  const int* srow = src + (size_t)n * KFAN;
  float acc = 0.f;
#pragma unroll
  for (int k = 0; k < KFAN; ++k) {
    int s = srow[k];      // uniform scalar load
    float w = wrow[k];    // uniform scalar load
    acc = fmaf(w, hin[(size_t)s * BDIM + lane], acc);  // 256B coalesced gather
  }
  hout[(size_t)n * BDIM + lane] = fmaxf(acc, 0.f);
}

constexpr int OC_NC = 256;
constexpr int OC_CHUNKS = (NV + OC_NC - 1) / OC_NC;  // 196

// partial[dtile][chunk][d_local][b] = sum over n-chunk of h[n][b]*Wout[d][n]
__global__ __launch_bounds__(256) void out_partial(
    const float* __restrict__ h, const float* __restrict__ Wout,
    float* __restrict__ part)
{
  __shared__ float hs[64][65];   // [n_local][b]
  __shared__ float wts[64][65];  // [n_local][d_local] (transposed stage)
  const int t = threadIdx.x;
  const int d0 = blockIdx.x * 64;
  const int n0 = blockIdx.y * OC_NC;
  const int tx = t & 15;   // b-group
  const int ty = t >> 4;   // d-group
  float acc[4][4] = {};    // [j -> d][i -> b]

  for (int ns = 0; ns < OC_NC; ns += 64) {
    const int nb = n0 + ns;
#pragma unroll
    for (int rep = 0; rep < 4; ++rep) {
      int idx = rep * 256 + t;
      int row = idx >> 4;
      int c4 = (idx & 15) * 4;
      int n = nb + row;
      float4 hv = make_float4(0.f, 0.f, 0.f, 0.f);
      if (n < NV) hv = *(const float4*)(h + (size_t)n * BDIM + c4);
      hs[row][c4 + 0] = hv.x; hs[row][c4 + 1] = hv.y;
      hs[row][c4 + 2] = hv.z; hs[row][c4 + 3] = hv.w;
      float4 wv = make_float4(0.f, 0.f, 0.f, 0.f);
      int nc = nb + c4;  // NV % 4 == 0, so float4 is all-in or all-out
      if (nc < NV) wv = *(const float4*)(Wout + (size_t)(d0 + row) * NV + nc);
      wts[c4 + 0][row] = wv.x; wts[c4 + 1][row] = wv.y;
      wts[c4 + 2][row] = wv.z; wts[c4 + 3][row] = wv.w;
    }
    __syncthreads();
#pragma unroll 8
    for (int nn = 0; nn < 64; ++nn) {
      float hb[4], wd[4];
#pragma unroll
      for (int i = 0; i < 4; ++i) hb[i] = hs[nn][tx * 4 + i];
#pragma unroll
      for (int j = 0; j < 4; ++j) wd[j] = wts[nn][ty * 4 + j];
#pragma unroll
      for (int j = 0; j < 4; ++j)
#pragma unroll
        for (int i = 0; i < 4; ++i)
          acc[j][i] = fmaf(wd[j], hb[i], acc[j][i]);
    }
    __syncthreads();
  }
  float* pbase = part + ((size_t)blockIdx.x * OC_CHUNKS + blockIdx.y) * (64 * 64);
#pragma unroll
  for (int j = 0; j < 4; ++j) {
    float4 o = make_float4(acc[j][0], acc[j][1], acc[j][2], acc[j][3]);
    *(float4*)(pbase + (ty * 4 + j) * 64 + tx * 4) = o;
  }
}

// out[b][d] = bout[d] + sum_chunks partial
__global__ __launch_bounds__(256) void out_reduce(
    const float* __restrict__ part, const float* __restrict__ bout,
    float* __restrict__ out)
{
  int tid = blockIdx.x * 256 + threadIdx.x;  // 16384 threads
  int b = tid & 63;
  int d = tid >> 6;
  int dtile = d >> 6;
  int dd = d & 63;
  float s = bout[d];
  for (int c = 0; c < OC_CHUNKS; ++c)
    s += part[((size_t)dtile * OC_CHUNKS + c) * 4096 + dd * 64 + b];
  out[(size_t)b * DOUT + d] = s;
}

extern "C" void kernel_launch(void* const* d_in, const int* in_sizes, int n_in,
                              void* d_out, int out_size, void* d_ws, size_t ws_size,
                              hipStream_t stream)
{
  const float* x    = (const float*)d_in[0];
  const float* W0   = (const float*)d_in[1];
  const float* b0   = (const float*)d_in[2];
  const float* Wv   = (const float*)d_in[3];
  const float* Wout = (const float*)d_in[4];
  const float* bout = (const float*)d_in[5];
  const int*   src  = (const int*)d_in[6];
  float* out = (float*)d_out;

  char* ws = (char*)d_ws;
  const size_t hbytes = (size_t)NV * BDIM * sizeof(float);  // 12.8 MB
  float* h0   = (float*)ws;
  float* h1   = (float*)(ws + hbytes);
  float* part = (float*)(ws + 2 * hbytes);  // 12.85 MB

  layer0_gemm<<<(NV + L0_BN - 1) / L0_BN, 256, 0, stream>>>(x, W0, b0, h0);

  const float* hin = h0;
  float* hout = h1;
  for (int l = 0; l < NLAYERS; ++l) {
    sparse_layer<<<NV / 4, 256, 0, stream>>>(
        hin, Wv + (size_t)l * NV * KFAN, src + (size_t)l * NV * KFAN, hout);
    float* tmp = (float*)hin; hin = hout; hout = tmp;
  }
  // after 3 swaps, hin points at the final h (h1)

  out_partial<<<dim3(4, OC_CHUNKS), 256, 0, stream>>>(hin, Wout, part);
  out_reduce<<<(BDIM * DOUT) / 256, 256, 0, stream>>>(part, bout, out);
}

// Round 2
// 366.649 us; speedup vs baseline: 1.0458x; 1.0458x over previous
//
#include <hip/hip_runtime.h>

#define NV 50000
#define BDIM 64
#define DIN 1024
#define KFAN 32
#define NLAYERS 3
#define DOUT 256

typedef float fx16 __attribute__((ext_vector_type(16)));

__device__ __forceinline__ void gload_lds16(const float* g, float* l) {
  __builtin_amdgcn_global_load_lds(
      (const __attribute__((address_space(1))) void*)g,
      (__attribute__((address_space(3))) void*)l, 16, 0, 0);
}

// h[n][b] = relu(sum_d W0[n][d]*x[b][d] + b0[n])
// block: 256 thr = 4 waves; lane = n-local (64 rows/block); wave = b-quarter (16 b each)
__global__ __launch_bounds__(256) void layer0_gemm(
    const float* __restrict__ x, const float* __restrict__ W0,
    const float* __restrict__ b0, float* __restrict__ h)
{
  __shared__ float wlds[2][64 * 32];  // double-buffered W tile [64 n][32 d], XOR-swizzled
  __shared__ float tlds[64][64];      // transpose buffer for coalesced store
  const int t = threadIdx.x;
  const int lane = t & 63;
  const int wv = __builtin_amdgcn_readfirstlane(t >> 6);  // b-quarter 0..3
  const int n0 = blockIdx.x * 64;
  const int nl = lane;
  const int n = n0 + nl;

  float acc[16];
#pragma unroll
  for (int j = 0; j < 16; ++j) acc[j] = 0.f;

  // ---- staging: W0 tile [64][32] floats, row = 128 B; swizzle source so
  // slot g16 of row holds source col-group (g16 ^ (row&7)); LDS dest linear.
  auto stage = [&](int buf, int c) {
#pragma unroll
    for (int p = 0; p < 2; ++p) {
      int flat = p * 256 + t;                 // 0..511, lane-linear per wave
      int row = flat >> 3;                    // 0..63
      int g16 = flat & 7;                     // 16B-group in row
      int srcb = (g16 << 4) ^ ((row & 7) << 4);  // swizzled byte-in-row
      int rowg = n0 + row;
      if (rowg > NV - 1) rowg = NV - 1;
      const float* src = W0 + (size_t)rowg * DIN + c * 32 + (srcb >> 2);
      gload_lds16(src, &wlds[buf][flat * 4]);
    }
  };

  stage(0, 0);
  __syncthreads();

  const float* xq_base = x + (size_t)(wv * 16) * DIN;

  for (int c = 0; c < 32; ++c) {
    if (c + 1 < 32) stage((c + 1) & 1, c + 1);

    // lane reads its W row: 8x ds_read_b128, conflict-free via XOR swizzle
    const float* wb = &wlds[c & 1][0];
    float4 wr[8];
#pragma unroll
    for (int i = 0; i < 8; ++i) {
      int offb = nl * 128 + ((i * 16) ^ ((nl & 7) << 4));
      wr[i] = *(const float4*)(wb + (offb >> 2));
    }

    // x[b][c*32 .. +31] via scalar loads, pipelined one b ahead
    const float* xp = xq_base + c * 32;
    fx16 xc0, xc1;
    asm volatile(
        "s_load_dwordx16 %0, %2, 0x0\n\t"
        "s_load_dwordx16 %1, %2, 0x40\n\t"
        "s_waitcnt lgkmcnt(0)"
        : "=s"(xc0), "=s"(xc1) : "s"(xp));

#pragma unroll
    for (int j = 0; j < 16; ++j) {
      fx16 xn0, xn1;
      if (j < 15) {
        const float* xq = xp + (size_t)(j + 1) * DIN;
        asm volatile(
            "s_load_dwordx16 %0, %2, 0x0\n\t"
            "s_load_dwordx16 %1, %2, 0x40"
            : "=s"(xn0), "=s"(xn1) : "s"(xq));
      }
      float a0 = acc[j], a1 = 0.f;  // two chains to cover FMA latency
#pragma unroll
      for (int i = 0; i < 8; ++i) {
#pragma unroll
        for (int e = 0; e < 4; ++e) {
          int d = i * 4 + e;
          float xv = (d < 16) ? xc0[d] : xc1[d - 16];
          float w = (e == 0) ? wr[i].x : (e == 1) ? wr[i].y : (e == 2) ? wr[i].z : wr[i].w;
          if (d & 1) a1 = fmaf(w, xv, a1); else a0 = fmaf(w, xv, a0);
        }
      }
      acc[j] = a0 + a1;
      if (j < 15) {
        asm volatile("s_waitcnt lgkmcnt(0)" : "+s"(xn0), "+s"(xn1));
        xc0 = xn0; xc1 = xn1;
      }
    }
    __syncthreads();
  }

  // ---- epilogue: bias + relu, LDS transpose (XOR col swizzle), coalesced store
  float bias = b0[n < NV ? n : 0];
#pragma unroll
  for (int j = 0; j < 16; ++j) {
    int b = wv * 16 + j;
    tlds[nl][b ^ (nl & 31)] = fmaxf(acc[j] + bias, 0.f);
  }
  __syncthreads();
  int r = t >> 2, q = t & 3;
  if (n0 + r < NV) {
    float o[16];
#pragma unroll
    for (int i = 0; i < 16; ++i) {
      int b = q * 16 + i;
      o[i] = tlds[r][b ^ (r & 31)];
    }
#pragma unroll
    for (int i2 = 0; i2 < 4; ++i2)
      *(float4*)(h + (size_t)(n0 + r) * BDIM + q * 16 + i2 * 4) =
          make_float4(o[i2 * 4], o[i2 * 4 + 1], o[i2 * 4 + 2], o[i2 * 4 + 3]);
  }
}

// h_new[n][b] = relu(sum_k wv[n][k] * h[src[n][k]][b]); one wave per n
__global__ __launch_bounds__(256) void sparse_layer(
    const float* __restrict__ hin, const float* __restrict__ wv,
    const int* __restrict__ src, float* __restrict__ hout)
{
  const int lane = threadIdx.x & 63;
  int n = blockIdx.x * 4 + (threadIdx.x >> 6);
  n = __builtin_amdgcn_readfirstlane(n);
  const float* wrow = wv + (size_t)n * KFAN;
  const int* srow = src + (size_t)n * KFAN;
  float acc = 0.f;
#pragma unroll
  for (int k = 0; k < KFAN; ++k) {
    int s = srow[k];
    float w = wrow[k];
    acc = fmaf(w, hin[(size_t)s * BDIM + lane], acc);
  }
  hout[(size_t)n * BDIM + lane] = fmaxf(acc, 0.f);
}

constexpr int OC_NC = 256;
constexpr int OC_CHUNKS = (NV + OC_NC - 1) / OC_NC;  // 196

__global__ __launch_bounds__(256) void out_partial(
    const float* __restrict__ h, const float* __restrict__ Wout,
    float* __restrict__ part)
{
  __shared__ float hs[64][65];
  __shared__ float wts[64][65];
  const int t = threadIdx.x;
  const int d0 = blockIdx.x * 64;
  const int n0 = blockIdx.y * OC_NC;
  const int tx = t & 15;
  const int ty = t >> 4;
  float acc[4][4] = {};

  for (int ns = 0; ns < OC_NC; ns += 64) {
    const int nb = n0 + ns;
#pragma unroll
    for (int rep = 0; rep < 4; ++rep) {
      int idx = rep * 256 + t;
      int row = idx >> 4;
      int c4 = (idx & 15) * 4;
      int nn = nb + row;
      float4 hv = make_float4(0.f, 0.f, 0.f, 0.f);
      if (nn < NV) hv = *(const float4*)(h + (size_t)nn * BDIM + c4);
      hs[row][c4 + 0] = hv.x; hs[row][c4 + 1] = hv.y;
      hs[row][c4 + 2] = hv.z; hs[row][c4 + 3] = hv.w;
      float4 wv = make_float4(0.f, 0.f, 0.f, 0.f);
      int nc = nb + c4;
      if (nc < NV) wv = *(const float4*)(Wout + (size_t)(d0 + row) * NV + nc);
      wts[c4 + 0][row] = wv.x; wts[c4 + 1][row] = wv.y;
      wts[c4 + 2][row] = wv.z; wts[c4 + 3][row] = wv.w;
    }
    __syncthreads();
#pragma unroll 8
    for (int nn = 0; nn < 64; ++nn) {
      float hb[4], wd[4];
#pragma unroll
      for (int i = 0; i < 4; ++i) hb[i] = hs[nn][tx * 4 + i];
#pragma unroll
      for (int j = 0; j < 4; ++j) wd[j] = wts[nn][ty * 4 + j];
#pragma unroll
      for (int j = 0; j < 4; ++j)
#pragma unroll
        for (int i = 0; i < 4; ++i)
          acc[j][i] = fmaf(wd[j], hb[i], acc[j][i]);
    }
    __syncthreads();
  }
  float* pbase = part + ((size_t)blockIdx.x * OC_CHUNKS + blockIdx.y) * (64 * 64);
#pragma unroll
  for (int j = 0; j < 4; ++j) {
    float4 o = make_float4(acc[j][0], acc[j][1], acc[j][2], acc[j][3]);
    *(float4*)(pbase + (ty * 4 + j) * 64 + tx * 4) = o;
  }
}

__global__ __launch_bounds__(256) void out_reduce(
    const float* __restrict__ part, const float* __restrict__ bout,
    float* __restrict__ out)
{
  int tid = blockIdx.x * 256 + threadIdx.x;
  int b = tid & 63;
  int d = tid >> 6;
  int dtile = d >> 6;
  int dd = d & 63;
  float s = bout[d];
  for (int c = 0; c < OC_CHUNKS; ++c)
    s += part[((size_t)dtile * OC_CHUNKS + c) * 4096 + dd * 64 + b];
  out[(size_t)b * DOUT + d] = s;
}

extern "C" void kernel_launch(void* const* d_in, const int* in_sizes, int n_in,
                              void* d_out, int out_size, void* d_ws, size_t ws_size,
                              hipStream_t stream)
{
  const float* x    = (const float*)d_in[0];
  const float* W0   = (const float*)d_in[1];
  const float* b0   = (const float*)d_in[2];
  const float* Wv   = (const float*)d_in[3];
  const float* Wout = (const float*)d_in[4];
  const float* bout = (const float*)d_in[5];
  const int*   src  = (const int*)d_in[6];
  float* out = (float*)d_out;

  char* ws = (char*)d_ws;
  const size_t hbytes = (size_t)NV * BDIM * sizeof(float);  // 12.8 MB
  float* h0   = (float*)ws;
  float* h1   = (float*)(ws + hbytes);
  float* part = (float*)(ws + 2 * hbytes);

  layer0_gemm<<<(NV + 63) / 64, 256, 0, stream>>>(x, W0, b0, h0);

  const float* hin = h0;
  float* hout = h1;
  for (int l = 0; l < NLAYERS; ++l) {
    sparse_layer<<<NV / 4, 256, 0, stream>>>(
        hin, Wv + (size_t)l * NV * KFAN, src + (size_t)l * NV * KFAN, hout);
    float* tmp = (float*)hin; hin = hout; hout = tmp;
  }

  out_partial<<<dim3(4, OC_CHUNKS), 256, 0, stream>>>(hin, Wout, part);
  out_reduce<<<(BDIM * DOUT) / 256, 256, 0, stream>>>(part, bout, out);
}

// Round 3
// 270.395 us; speedup vs baseline: 1.4181x; 1.3560x over previous
//
#include <hip/hip_runtime.h>

#define NV 50000
#define BDIM 64
#define DIN 1024
#define KFAN 32
#define NLAYERS 3
#define DOUT 256
#define KSTEPS (DIN / 32)

typedef short bf16x8 __attribute__((ext_vector_type(8)));
typedef float f32x4 __attribute__((ext_vector_type(4)));

__device__ __forceinline__ unsigned short bf16_rtn(float f) {
  unsigned u = __float_as_uint(f);
  return (unsigned short)((u + 0x7fffu + ((u >> 16) & 1u)) >> 16);
}

// Pack x[64][1024] into MFMA B-fragment lane order, split into hi/lo bf16.
// Layout: xpk[(ks*4+g)*128 + h*64 + lane] (uint4), h=0 hi, h=1 lo.
// B-frag for 16x16x32: lane holds B[k=(lane>>4)*8+j][col=lane&15], j=0..7,
// with B[k][col] = x[g*16+col][ks*32+k].
__global__ __launch_bounds__(256) void pack_x(const float* __restrict__ x,
                                              uint4* __restrict__ xpk) {
  int tid = blockIdx.x * 256 + threadIdx.x;  // 0..8191
  int ks = tid >> 8;
  int g = (tid >> 6) & 3;
  int l = tid & 63;
  int b = g * 16 + (l & 15);
  int k0 = ks * 32 + (l >> 4) * 8;
  unsigned hi[8], lo[8];
#pragma unroll
  for (int j = 0; j < 8; ++j) {
    float f = x[b * DIN + k0 + j];
    unsigned u = __float_as_uint(f);
    hi[j] = u >> 16;  // truncate to bf16
    float fh = __uint_as_float(u & 0xffff0000u);
    lo[j] = bf16_rtn(f - fh);
  }
  uint4 vh, vl;
  vh.x = hi[0] | (hi[1] << 16); vh.y = hi[2] | (hi[3] << 16);
  vh.z = hi[4] | (hi[5] << 16); vh.w = hi[6] | (hi[7] << 16);
  vl.x = lo[0] | (lo[1] << 16); vl.y = lo[2] | (lo[3] << 16);
  vl.z = lo[4] | (lo[5] << 16); vl.w = lo[6] | (lo[7] << 16);
  xpk[(ks * 4 + g) * 128 + l] = vh;
  xpk[(ks * 4 + g) * 128 + 64 + l] = vl;
}

// h[n][b] = relu(sum_d W0[n][d]*x[b][d] + b0[n]) via split-bf16 MFMA.
// One wave per 32 n-rows: 2 A-frags (16 rows each) x 4 b-colgroups.
// W0 streamed HBM->VGPR (no reuse); x-frags from L2-resident packed buffer.
__global__ __launch_bounds__(64) void layer0_mfma(
    const float* __restrict__ W0, const float* __restrict__ b0,
    const uint4* __restrict__ xpk, float* __restrict__ h)
{
  const int lane = threadIdx.x;
  const int n_base = blockIdx.x * 32;
  const int rq = lane >> 4;   // k-quarter (A) / k-quarter (B) / row-quad (C)
  const int rr = lane & 15;   // row-in-frag (A) / col (B,C)

  int r0 = n_base + rr;       if (r0 > NV - 1) r0 = NV - 1;
  int r1 = n_base + 16 + rr;  if (r1 > NV - 1) r1 = NV - 1;
  const float* wp0 = W0 + (size_t)r0 * DIN + rq * 8;
  const float* wp1 = W0 + (size_t)r1 * DIN + rq * 8;

  f32x4 acc[2][4];
#pragma unroll
  for (int f = 0; f < 2; ++f)
#pragma unroll
    for (int g = 0; g < 4; ++g) acc[f][g] = (f32x4){0.f, 0.f, 0.f, 0.f};

  float4 wc[2][2];
  uint4 xc[4][2];
  wc[0][0] = *(const float4*)(wp0);
  wc[0][1] = *(const float4*)(wp0 + 4);
  wc[1][0] = *(const float4*)(wp1);
  wc[1][1] = *(const float4*)(wp1 + 4);
#pragma unroll
  for (int g = 0; g < 4; ++g) {
    xc[g][0] = xpk[g * 128 + lane];
    xc[g][1] = xpk[g * 128 + 64 + lane];
  }

  for (int ks = 0; ks < KSTEPS; ++ks) {
    float4 wn[2][2];
    uint4 xn[4][2];
    if (ks + 1 < KSTEPS) {
      const int ko = (ks + 1) * 32;
      wn[0][0] = *(const float4*)(wp0 + ko);
      wn[0][1] = *(const float4*)(wp0 + ko + 4);
      wn[1][0] = *(const float4*)(wp1 + ko);
      wn[1][1] = *(const float4*)(wp1 + ko + 4);
      const int xb = (ks + 1) * 512;
#pragma unroll
      for (int g = 0; g < 4; ++g) {
        xn[g][0] = xpk[xb + g * 128 + lane];
        xn[g][1] = xpk[xb + g * 128 + 64 + lane];
      }
    }
    // split W fragments into hi/lo bf16
    bf16x8 whi[2], wlo[2];
#pragma unroll
    for (int f = 0; f < 2; ++f) {
      float wf[8] = {wc[f][0].x, wc[f][0].y, wc[f][0].z, wc[f][0].w,
                     wc[f][1].x, wc[f][1].y, wc[f][1].z, wc[f][1].w};
#pragma unroll
      for (int e = 0; e < 8; ++e) {
        unsigned u = __float_as_uint(wf[e]);
        whi[f][e] = (short)(u >> 16);
        float l = wf[e] - __uint_as_float(u & 0xffff0000u);
        wlo[f][e] = (short)bf16_rtn(l);
      }
    }
    bf16x8 xh[4], xl[4];
#pragma unroll
    for (int g = 0; g < 4; ++g) {
      xh[g] = __builtin_bit_cast(bf16x8, xc[g][0]);
      xl[g] = __builtin_bit_cast(bf16x8, xc[g][1]);
    }
#pragma unroll
    for (int f = 0; f < 2; ++f)
#pragma unroll
      for (int g = 0; g < 4; ++g) {
        acc[f][g] = __builtin_amdgcn_mfma_f32_16x16x32_bf16(whi[f], xh[g], acc[f][g], 0, 0, 0);
        acc[f][g] = __builtin_amdgcn_mfma_f32_16x16x32_bf16(wlo[f], xh[g], acc[f][g], 0, 0, 0);
        acc[f][g] = __builtin_amdgcn_mfma_f32_16x16x32_bf16(whi[f], xl[g], acc[f][g], 0, 0, 0);
      }
    if (ks + 1 < KSTEPS) {
#pragma unroll
      for (int f = 0; f < 2; ++f) { wc[f][0] = wn[f][0]; wc[f][1] = wn[f][1]; }
#pragma unroll
      for (int g = 0; g < 4; ++g) { xc[g][0] = xn[g][0]; xc[g][1] = xn[g][1]; }
    }
  }

  // epilogue: C layout col=lane&15, row=(lane>>4)*4+reg
#pragma unroll
  for (int f = 0; f < 2; ++f)
#pragma unroll
    for (int r = 0; r < 4; ++r) {
      int n = n_base + f * 16 + rq * 4 + r;
      if (n < NV) {
        float bias = b0[n];
#pragma unroll
        for (int g = 0; g < 4; ++g) {
          float v = fmaxf(acc[f][g][r] + bias, 0.f);
          h[(size_t)n * BDIM + g * 16 + rr] = v;
        }
      }
    }
}

// h_new[n][b] = relu(sum_k wv[n][k] * h[src[n][k]][b]); one wave per n
__global__ __launch_bounds__(256) void sparse_layer(
    const float* __restrict__ hin, const float* __restrict__ wv,
    const int* __restrict__ src, float* __restrict__ hout)
{
  const int lane = threadIdx.x & 63;
  int n = blockIdx.x * 4 + (threadIdx.x >> 6);
  n = __builtin_amdgcn_readfirstlane(n);
  const float* wrow = wv + (size_t)n * KFAN;
  const int* srow = src + (size_t)n * KFAN;
  float acc = 0.f;
#pragma unroll
  for (int k = 0; k < KFAN; ++k) {
    int s = srow[k];
    float w = wrow[k];
    acc = fmaf(w, hin[(size_t)s * BDIM + lane], acc);
  }
  hout[(size_t)n * BDIM + lane] = fmaxf(acc, 0.f);
}

constexpr int OC_NC = 256;
constexpr int OC_CHUNKS = (NV + OC_NC - 1) / OC_NC;  // 196

__global__ __launch_bounds__(256) void out_partial(
    const float* __restrict__ h, const float* __restrict__ Wout,
    float* __restrict__ part)
{
  __shared__ float hs[64][65];
  __shared__ float wts[64][65];
  const int t = threadIdx.x;
  const int d0 = blockIdx.x * 64;
  const int n0 = blockIdx.y * OC_NC;
  const int tx = t & 15;
  const int ty = t >> 4;
  float acc[4][4] = {};

  for (int ns = 0; ns < OC_NC; ns += 64) {
    const int nb = n0 + ns;
#pragma unroll
    for (int rep = 0; rep < 4; ++rep) {
      int idx = rep * 256 + t;
      int row = idx >> 4;
      int c4 = (idx & 15) * 4;
      int nn = nb + row;
      float4 hv = make_float4(0.f, 0.f, 0.f, 0.f);
      if (nn < NV) hv = *(const float4*)(h + (size_t)nn * BDIM + c4);
      hs[row][c4 + 0] = hv.x; hs[row][c4 + 1] = hv.y;
      hs[row][c4 + 2] = hv.z; hs[row][c4 + 3] = hv.w;
      float4 wv = make_float4(0.f, 0.f, 0.f, 0.f);
      int nc = nb + c4;
      if (nc < NV) wv = *(const float4*)(Wout + (size_t)(d0 + row) * NV + nc);
      wts[c4 + 0][row] = wv.x; wts[c4 + 1][row] = wv.y;
      wts[c4 + 2][row] = wv.z; wts[c4 + 3][row] = wv.w;
    }
    __syncthreads();
#pragma unroll 8
    for (int nn = 0; nn < 64; ++nn) {
      float hb[4], wd[4];
#pragma unroll
      for (int i = 0; i < 4; ++i) hb[i] = hs[nn][tx * 4 + i];
#pragma unroll
      for (int j = 0; j < 4; ++j) wd[j] = wts[nn][ty * 4 + j];
#pragma unroll
      for (int j = 0; j < 4; ++j)
#pragma unroll
        for (int i = 0; i < 4; ++i)
          acc[j][i] = fmaf(wd[j], hb[i], acc[j][i]);
    }
    __syncthreads();
  }
  float* pbase = part + ((size_t)blockIdx.x * OC_CHUNKS + blockIdx.y) * (64 * 64);
#pragma unroll
  for (int j = 0; j < 4; ++j) {
    float4 o = make_float4(acc[j][0], acc[j][1], acc[j][2], acc[j][3]);
    *(float4*)(pbase + (ty * 4 + j) * 64 + tx * 4) = o;
  }
}

__global__ __launch_bounds__(256) void out_reduce(
    const float* __restrict__ part, const float* __restrict__ bout,
    float* __restrict__ out)
{
  int tid = blockIdx.x * 256 + threadIdx.x;
  int b = tid & 63;
  int d = tid >> 6;
  int dtile = d >> 6;
  int dd = d & 63;
  float s = bout[d];
  for (int c = 0; c < OC_CHUNKS; ++c)
    s += part[((size_t)dtile * OC_CHUNKS + c) * 4096 + dd * 64 + b];
  out[(size_t)b * DOUT + d] = s;
}

extern "C" void kernel_launch(void* const* d_in, const int* in_sizes, int n_in,
                              void* d_out, int out_size, void* d_ws, size_t ws_size,
                              hipStream_t stream)
{
  const float* x    = (const float*)d_in[0];
  const float* W0   = (const float*)d_in[1];
  const float* b0   = (const float*)d_in[2];
  const float* Wv   = (const float*)d_in[3];
  const float* Wout = (const float*)d_in[4];
  const float* bout = (const float*)d_in[5];
  const int*   src  = (const int*)d_in[6];
  float* out = (float*)d_out;

  char* ws = (char*)d_ws;
  const size_t hbytes = (size_t)NV * BDIM * sizeof(float);  // 12.8 MB
  float* h0 = (float*)ws;
  float* h1 = (float*)(ws + hbytes);
  // xpk and part share the same region: xpk is consumed by layer0_mfma
  // before out_partial writes part. (xpk = 256 KB, part = 12.85 MB)
  uint4* xpk  = (uint4*)(ws + 2 * hbytes);
  float* part = (float*)(ws + 2 * hbytes);

  pack_x<<<32, 256, 0, stream>>>(x, xpk);
  layer0_mfma<<<(NV + 31) / 32, 64, 0, stream>>>(W0, b0, xpk, h0);

  const float* hin = h0;
  float* hout = h1;
  for (int l = 0; l < NLAYERS; ++l) {
    sparse_layer<<<NV / 4, 256, 0, stream>>>(
        hin, Wv + (size_t)l * NV * KFAN, src + (size_t)l * NV * KFAN, hout);
    float* tmp = (float*)hin; hin = hout; hout = tmp;
  }

  out_partial<<<dim3(4, OC_CHUNKS), 256, 0, stream>>>(hin, Wout, part);
  out_reduce<<<(BDIM * DOUT) / 256, 256, 0, stream>>>(part, bout, out);
}

// Round 4
// 204.100 us; speedup vs baseline: 1.8787x; 1.3248x over previous
//
#include <hip/hip_runtime.h>

#define NV 50000
#define BDIM 64
#define DIN 1024
#define KFAN 32
#define DOUT 256
#define KSTEPS (DIN / 32)

typedef short bf16x8 __attribute__((ext_vector_type(8)));
typedef float f32x4 __attribute__((ext_vector_type(4)));

__device__ __forceinline__ unsigned short bf16_rtn(float f) {
  unsigned u = __float_as_uint(f);
  return (unsigned short)((u + 0x7fffu + ((u >> 16) & 1u)) >> 16);
}
__device__ __forceinline__ float bf16_to_f(unsigned short v) {
  return __uint_as_float(((unsigned)v) << 16);
}

// Pack x[64][1024] into MFMA B-fragment lane order, split into hi/lo bf16.
__global__ __launch_bounds__(256) void pack_x(const float* __restrict__ x,
                                              uint4* __restrict__ xpk) {
  int tid = blockIdx.x * 256 + threadIdx.x;  // 0..8191
  int ks = tid >> 8;
  int g = (tid >> 6) & 3;
  int l = tid & 63;
  int b = g * 16 + (l & 15);
  int k0 = ks * 32 + (l >> 4) * 8;
  unsigned hi[8], lo[8];
#pragma unroll
  for (int j = 0; j < 8; ++j) {
    float f = x[b * DIN + k0 + j];
    unsigned u = __float_as_uint(f);
    hi[j] = u >> 16;  // truncate to bf16
    float fh = __uint_as_float(u & 0xffff0000u);
    lo[j] = bf16_rtn(f - fh);
  }
  uint4 vh, vl;
  vh.x = hi[0] | (hi[1] << 16); vh.y = hi[2] | (hi[3] << 16);
  vh.z = hi[4] | (hi[5] << 16); vh.w = hi[6] | (hi[7] << 16);
  vl.x = lo[0] | (lo[1] << 16); vl.y = lo[2] | (lo[3] << 16);
  vl.z = lo[4] | (lo[5] << 16); vl.w = lo[6] | (lo[7] << 16);
  xpk[(ks * 4 + g) * 128 + l] = vh;
  xpk[(ks * 4 + g) * 128 + 64 + l] = vl;
}

// h[n][b] = relu(sum_d W0[n][d]*x[b][d] + b0[n]) via split-bf16 MFMA.
// Output stored as bf16 (rtn).
__global__ __launch_bounds__(64) void layer0_mfma(
    const float* __restrict__ W0, const float* __restrict__ b0,
    const uint4* __restrict__ xpk, unsigned short* __restrict__ h)
{
  const int lane = threadIdx.x;
  const int n_base = blockIdx.x * 32;
  const int rq = lane >> 4;
  const int rr = lane & 15;

  int r0 = n_base + rr;       if (r0 > NV - 1) r0 = NV - 1;
  int r1 = n_base + 16 + rr;  if (r1 > NV - 1) r1 = NV - 1;
  const float* wp0 = W0 + (size_t)r0 * DIN + rq * 8;
  const float* wp1 = W0 + (size_t)r1 * DIN + rq * 8;

  f32x4 acc[2][4];
#pragma unroll
  for (int f = 0; f < 2; ++f)
#pragma unroll
    for (int g = 0; g < 4; ++g) acc[f][g] = (f32x4){0.f, 0.f, 0.f, 0.f};

  float4 wc[2][2];
  uint4 xc[4][2];
  wc[0][0] = *(const float4*)(wp0);
  wc[0][1] = *(const float4*)(wp0 + 4);
  wc[1][0] = *(const float4*)(wp1);
  wc[1][1] = *(const float4*)(wp1 + 4);
#pragma unroll
  for (int g = 0; g < 4; ++g) {
    xc[g][0] = xpk[g * 128 + lane];
    xc[g][1] = xpk[g * 128 + 64 + lane];
  }

  for (int ks = 0; ks < KSTEPS; ++ks) {
    float4 wn[2][2];
    uint4 xn[4][2];
    if (ks + 1 < KSTEPS) {
      const int ko = (ks + 1) * 32;
      wn[0][0] = *(const float4*)(wp0 + ko);
      wn[0][1] = *(const float4*)(wp0 + ko + 4);
      wn[1][0] = *(const float4*)(wp1 + ko);
      wn[1][1] = *(const float4*)(wp1 + ko + 4);
      const int xb = (ks + 1) * 512;
#pragma unroll
      for (int g = 0; g < 4; ++g) {
        xn[g][0] = xpk[xb + g * 128 + lane];
        xn[g][1] = xpk[xb + g * 128 + 64 + lane];
      }
    }
    bf16x8 whi[2], wlo[2];
#pragma unroll
    for (int f = 0; f < 2; ++f) {
      float wf[8] = {wc[f][0].x, wc[f][0].y, wc[f][0].z, wc[f][0].w,
                     wc[f][1].x, wc[f][1].y, wc[f][1].z, wc[f][1].w};
#pragma unroll
      for (int e = 0; e < 8; ++e) {
        unsigned u = __float_as_uint(wf[e]);
        whi[f][e] = (short)(u >> 16);
        float l = wf[e] - __uint_as_float(u & 0xffff0000u);
        wlo[f][e] = (short)bf16_rtn(l);
      }
    }
    bf16x8 xh[4], xl[4];
#pragma unroll
    for (int g = 0; g < 4; ++g) {
      xh[g] = __builtin_bit_cast(bf16x8, xc[g][0]);
      xl[g] = __builtin_bit_cast(bf16x8, xc[g][1]);
    }
#pragma unroll
    for (int f = 0; f < 2; ++f)
#pragma unroll
      for (int g = 0; g < 4; ++g) {
        acc[f][g] = __builtin_amdgcn_mfma_f32_16x16x32_bf16(whi[f], xh[g], acc[f][g], 0, 0, 0);
        acc[f][g] = __builtin_amdgcn_mfma_f32_16x16x32_bf16(wlo[f], xh[g], acc[f][g], 0, 0, 0);
        acc[f][g] = __builtin_amdgcn_mfma_f32_16x16x32_bf16(whi[f], xl[g], acc[f][g], 0, 0, 0);
      }
    if (ks + 1 < KSTEPS) {
#pragma unroll
      for (int f = 0; f < 2; ++f) { wc[f][0] = wn[f][0]; wc[f][1] = wn[f][1]; }
#pragma unroll
      for (int g = 0; g < 4; ++g) { xc[g][0] = xn[g][0]; xc[g][1] = xn[g][1]; }
    }
  }

#pragma unroll
  for (int f = 0; f < 2; ++f)
#pragma unroll
    for (int r = 0; r < 4; ++r) {
      int n = n_base + f * 16 + rq * 4 + r;
      if (n < NV) {
        float bias = b0[n];
#pragma unroll
        for (int g = 0; g < 4; ++g) {
          float v = fmaxf(acc[f][g][r] + bias, 0.f);
          h[(size_t)n * BDIM + g * 16 + rr] = bf16_rtn(v);
        }
      }
    }
}

// h_new[n][b] = relu(sum_k wv[n][k] * h[src[n][k]][b]); one wave per n.
// hin is bf16 (128B rows); output bf16 or fp32 (last layer).
template <int OUTF32>
__global__ __launch_bounds__(256) void sparse_layer(
    const unsigned short* __restrict__ hin, const float* __restrict__ wv,
    const int* __restrict__ src, void* __restrict__ hout_)
{
  const int lane = threadIdx.x & 63;
  int n = blockIdx.x * 4 + (threadIdx.x >> 6);
  n = __builtin_amdgcn_readfirstlane(n);
  const float* wrow = wv + (size_t)n * KFAN;
  const int* srow = src + (size_t)n * KFAN;
  float acc = 0.f;
#pragma unroll
  for (int k = 0; k < KFAN; ++k) {
    int s = srow[k];      // uniform scalar load
    float w = wrow[k];    // uniform scalar load
    acc = fmaf(w, bf16_to_f(hin[(size_t)s * BDIM + lane]), acc);
  }
  acc = fmaxf(acc, 0.f);
  if (OUTF32)
    ((float*)hout_)[(size_t)n * BDIM + lane] = acc;
  else
    ((unsigned short*)hout_)[(size_t)n * BDIM + lane] = bf16_rtn(acc);
}

constexpr int OC_NC = 256;
constexpr int OC_CHUNKS = (NV + OC_NC - 1) / OC_NC;  // 196

__global__ __launch_bounds__(256) void out_partial(
    const float* __restrict__ h, const float* __restrict__ Wout,
    float* __restrict__ part)
{
  __shared__ float hs[64][65];
  __shared__ float wts[64][65];
  const int t = threadIdx.x;
  const int d0 = blockIdx.x * 64;
  const int n0 = blockIdx.y * OC_NC;
  const int tx = t & 15;
  const int ty = t >> 4;
  float acc[4][4] = {};

  for (int ns = 0; ns < OC_NC; ns += 64) {
    const int nb = n0 + ns;
#pragma unroll
    for (int rep = 0; rep < 4; ++rep) {
      int idx = rep * 256 + t;
      int row = idx >> 4;
      int c4 = (idx & 15) * 4;
      int nn = nb + row;
      float4 hv = make_float4(0.f, 0.f, 0.f, 0.f);
      if (nn < NV) hv = *(const float4*)(h + (size_t)nn * BDIM + c4);
      hs[row][c4 + 0] = hv.x; hs[row][c4 + 1] = hv.y;
      hs[row][c4 + 2] = hv.z; hs[row][c4 + 3] = hv.w;
      float4 wv = make_float4(0.f, 0.f, 0.f, 0.f);
      int nc = nb + c4;
      if (nc < NV) wv = *(const float4*)(Wout + (size_t)(d0 + row) * NV + nc);
      wts[c4 + 0][row] = wv.x; wts[c4 + 1][row] = wv.y;
      wts[c4 + 2][row] = wv.z; wts[c4 + 3][row] = wv.w;
    }
    __syncthreads();
#pragma unroll 8
    for (int nn = 0; nn < 64; ++nn) {
      float hb[4], wd[4];
#pragma unroll
      for (int i = 0; i < 4; ++i) hb[i] = hs[nn][tx * 4 + i];
#pragma unroll
      for (int j = 0; j < 4; ++j) wd[j] = wts[nn][ty * 4 + j];
#pragma unroll
      for (int j = 0; j < 4; ++j)
#pragma unroll
        for (int i = 0; i < 4; ++i)
          acc[j][i] = fmaf(wd[j], hb[i], acc[j][i]);
    }
    __syncthreads();
  }
  float* pbase = part + ((size_t)blockIdx.x * OC_CHUNKS + blockIdx.y) * (64 * 64);
#pragma unroll
  for (int j = 0; j < 4; ++j) {
    float4 o = make_float4(acc[j][0], acc[j][1], acc[j][2], acc[j][3]);
    *(float4*)(pbase + (ty * 4 + j) * 64 + tx * 4) = o;
  }
}

__global__ __launch_bounds__(256) void out_reduce(
    const float* __restrict__ part, const float* __restrict__ bout,
    float* __restrict__ out)
{
  int tid = blockIdx.x * 256 + threadIdx.x;
  int b = tid & 63;
  int d = tid >> 6;
  int dtile = d >> 6;
  int dd = d & 63;
  float s = bout[d];
  for (int c = 0; c < OC_CHUNKS; ++c)
    s += part[((size_t)dtile * OC_CHUNKS + c) * 4096 + dd * 64 + b];
  out[(size_t)b * DOUT + d] = s;
}

extern "C" void kernel_launch(void* const* d_in, const int* in_sizes, int n_in,
                              void* d_out, int out_size, void* d_ws, size_t ws_size,
                              hipStream_t stream)
{
  const float* x    = (const float*)d_in[0];
  const float* W0   = (const float*)d_in[1];
  const float* b0   = (const float*)d_in[2];
  const float* Wv   = (const float*)d_in[3];
  const float* Wout = (const float*)d_in[4];
  const float* bout = (const float*)d_in[5];
  const int*   src  = (const int*)d_in[6];
  float* out = (float*)d_out;

  char* ws = (char*)d_ws;
  const size_t hbf_bytes = (size_t)NV * BDIM * 2;  // 6.4 MB per bf16 h
  unsigned short* hb0 = (unsigned short*)ws;
  unsigned short* hb1 = (unsigned short*)(ws + hbf_bytes);
  float* hf = (float*)(ws + 2 * hbf_bytes);                     // 12.8 MB fp32 final h
  uint4* xpk  = (uint4*)(ws + 2 * hbf_bytes + (size_t)NV * BDIM * 4);
  float* part = (float*)(ws + 2 * hbf_bytes + (size_t)NV * BDIM * 4);  // aliases xpk (disjoint lifetime)

  pack_x<<<32, 256, 0, stream>>>(x, xpk);
  layer0_mfma<<<(NV + 31) / 32, 64, 0, stream>>>(W0, b0, xpk, hb0);

  const size_t lstride = (size_t)NV * KFAN;
  sparse_layer<0><<<NV / 4, 256, 0, stream>>>(hb0, Wv, src, hb1);
  sparse_layer<0><<<NV / 4, 256, 0, stream>>>(hb1, Wv + lstride, src + lstride, hb0);
  sparse_layer<1><<<NV / 4, 256, 0, stream>>>(hb0, Wv + 2 * lstride, src + 2 * lstride, hf);

  out_partial<<<dim3(4, OC_CHUNKS), 256, 0, stream>>>(hf, Wout, part);
  out_reduce<<<(BDIM * DOUT) / 256, 256, 0, stream>>>(part, bout, out);
}